// Round 7
// baseline (335.057 us; speedup 1.0000x reference)
//
#include <hip/hip_runtime.h>
#include <hip/hip_bf16.h>
#include <math.h>

#define N_NODES 50000
#define N_EDGES 1600000
#define IN_DIM  128
#define OUT_DIM 32
#define N_HEADS 4
#define WH_DIM  (N_HEADS * OUT_DIM)   // 128
#define CAP     96                    // per-node LDS edge cache (max deg ~58)
#define NB_SCAN 196                   // ceil(50000/256)
#define NPASS   4                     // dst-windows
#define WIN     (N_NODES / NPASS)     // 12500
#define NCHUNK  32                    // edge chunks for counting sort
#define CE      (N_EDGES / NCHUNK)    // 50000 edges per chunk

typedef __attribute__((ext_vector_type(8))) short short8;     // 8 bf16
typedef __attribute__((ext_vector_type(4))) float floatx4;    // MFMA acc

__device__ __forceinline__ short f2bf(float v) {
    __hip_bfloat16 b = __float2bfloat16(v);
    return *reinterpret_cast<short*>(&b);
}
__device__ __forceinline__ float lrelu(float v) {
    return v > 0.0f ? v : 0.2f * v;
}

// ---------------------------------------------------------------------------
// edge_index may arrive as int32 or int64 (reference dtype). For int64, odd
// 32-bit words are zero hi-words; sample 256 of them. Single block, LDS OR,
// unconditional flag store (no memset needed).
// ---------------------------------------------------------------------------
__device__ __forceinline__ void load_edge(const void* eidx, int is32, int e,
                                          int& s, int& d) {
    if (is32) {
        const int2 v = ((const int2*)eidx)[e];
        s = v.x; d = v.y;
    } else {
        const longlong2 v = ((const longlong2*)eidx)[e];
        s = (int)v.x; d = (int)v.y;
    }
}

__global__ void k_detect(const int* __restrict__ eidx, int* __restrict__ flag) {
    __shared__ int sf;
    if (threadIdx.x == 0) sf = 0;
    __syncthreads();
    int r = eidx[2 * (threadIdx.x * (N_EDGES / 256)) + 1];
    if (r != 0) sf = 1;                        // benign race, all write 1
    __syncthreads();
    if (threadIdx.x == 0) *flag = sf;          // nonzero hi-word => int32
}

// ---------------------------------------------------------------------------
// k_cvt: canonicalize edges to int32 SoA (coalesced, no atomics)
// ---------------------------------------------------------------------------
__global__ __launch_bounds__(256) void k_cvt(
        const void* __restrict__ eidx, const int* __restrict__ flag,
        int* __restrict__ s32, int* __restrict__ d32) {
    int e = blockIdx.x * 256 + threadIdx.x;
    if (e >= N_EDGES) return;
    int s, d;
    load_edge(eidx, *flag, e, s, d);
    s32[e] = s;
    d32[e] = d;
}

// ---------------------------------------------------------------------------
// MFMA GEMM: [64 nodes] x [144 cols] per block, K=128, bf16 inputs.
//   cols   0..127 : Wh, stored HEAD-MAJOR: Whh[h][n][32] bf16
//   cols 128..135 : s = x . U ;  U[k][c] = sum_o W[h][k][o]*a[h][o]
//                   (c<4: a_src head c ; c>=4: a_dst head c-4)
//                   stored sv[h][n] = {s_src, s_dst} float2
// ---------------------------------------------------------------------------
__global__ __launch_bounds__(256) void k_wh(
        const float* __restrict__ x, const float* __restrict__ weight,
        const float* __restrict__ attn,
        __hip_bfloat16* __restrict__ Whh, float* __restrict__ sv) {
    __shared__ float ubuf[128 * 8];            // 4 KB
    __shared__ short xsw[4 * 4 * 64 * 8];      // 16 KB  [wg][kc][lane][j]
    __shared__ short bsw[4 * 9 * 64 * 8];      // 36 KB  [kc][cg][lane][j]
    const int t  = threadIdx.x;
    const int nb = blockIdx.x * 64;

    // ---- U[k][c], c in [0,8)
    {
        int c = t & 7, k0 = t >> 3;            // k0 in [0,32)
        int h = c & 3;
        const float* ap = attn + h * 64 + (c >> 2) * 32;
        for (int k = k0; k < 128; k += 32) {
            const float* wp = weight + h * (IN_DIM * OUT_DIM) + k * OUT_DIM;
            float u = 0.f;
#pragma unroll
            for (int o = 0; o < 32; o += 4) {
                float4 wv = *(const float4*)(wp + o);
                float4 av = *(const float4*)(ap + o);
                u += wv.x * av.x + wv.y * av.y + wv.z * av.z + wv.w * av.w;
            }
            ubuf[k * 8 + c] = u;
        }
    }
    __syncthreads();

    // ---- stage B: weight cols 0..127
    for (int f = t; f < 128 * 128; f += 256) {
        int k = f >> 7, c = f & 127;
        float w = weight[(c >> 5) * (IN_DIM * OUT_DIM) + k * OUT_DIM + (c & 31)];
        int kc = k >> 5, quad = (k >> 3) & 3, j = k & 7;
        bsw[((kc * 9 + (c >> 4)) * 64 + quad * 16 + (c & 15)) * 8 + j] = f2bf(w);
    }
    // ---- stage B: extension cols 128..143 (U, zero-padded)
    for (int f = t; f < 128 * 16; f += 256) {
        int k = f >> 4, c = f & 15;
        float w = (c < 8) ? ubuf[k * 8 + c] : 0.f;
        int kc = k >> 5, quad = (k >> 3) & 3, j = k & 7;
        bsw[((kc * 9 + 8) * 64 + quad * 16 + c) * 8 + j] = f2bf(w);
    }
    // ---- stage A: 64 node rows of x, f32 -> bf16, swizzled
    for (int f = t; f < 64 * 32; f += 256) {
        int n = f >> 5, k = (f & 31) * 4;
        int ng = nb + n; if (ng > N_NODES - 1) ng = N_NODES - 1;
        float4 v = *(const float4*)(x + (size_t)ng * IN_DIM + k);
        int wg = n >> 4, m = n & 15, kc = k >> 5, quad = (k >> 3) & 3, j = k & 7;
        short4 sv4 = make_short4(f2bf(v.x), f2bf(v.y), f2bf(v.z), f2bf(v.w));
        *(short4*)&xsw[(((wg * 4 + kc) * 64) + quad * 16 + m) * 8 + j] = sv4;
    }
    __syncthreads();

    // ---- compute: per wave, 16 nodes x 144 cols, 36 MFMAs
    const int wg = t >> 6, lane = t & 63;
    floatx4 acc[9];
#pragma unroll
    for (int i = 0; i < 9; ++i) acc[i] = (floatx4){0.f, 0.f, 0.f, 0.f};
#pragma unroll
    for (int kc = 0; kc < 4; ++kc) {
        short8 a = *(short8*)&xsw[((wg * 4 + kc) * 64 + lane) * 8];
#pragma unroll
        for (int cg = 0; cg < 9; ++cg) {
            short8 b = *(short8*)&bsw[((kc * 9 + cg) * 64 + lane) * 8];
            acc[cg] = __builtin_amdgcn_mfma_f32_16x16x32_bf16(a, b, acc[cg],
                                                              0, 0, 0);
        }
    }

    // ---- epilogue (head-major stores)
    const int col = lane & 15, quad = lane >> 4;
#pragma unroll
    for (int r = 0; r < 4; ++r) {
        int n = nb + wg * 16 + quad * 4 + r;
        if (n >= N_NODES) continue;
#pragma unroll
        for (int cg = 0; cg < 8; ++cg)
            Whh[((size_t)(cg >> 1) * N_NODES + n) * 32 + (cg & 1) * 16 + col] =
                __float2bfloat16(acc[cg][r]);
        if (col < 8) {
            int hh = col & 3, side = col >> 2;
            sv[((size_t)hh * N_NODES + n) * 2 + side] = acc[8][r];
        }
    }
}

// ---------------------------------------------------------------------------
// k_hist: (chunk, window) blocks; LDS histogram, coalesced flush, no atomics.
// ---------------------------------------------------------------------------
__global__ __launch_bounds__(1024) void k_hist(
        const int* __restrict__ d32, int* __restrict__ hist) {
    __shared__ int hbin[WIN];                  // 50 KB
    const int c = blockIdx.x, w = blockIdx.y;
    for (int i = threadIdx.x; i < WIN; i += 1024) hbin[i] = 0;
    __syncthreads();
    const int w0 = w * WIN;
    for (int e = c * CE + threadIdx.x; e < (c + 1) * CE; e += 1024) {
        unsigned u = (unsigned)(d32[e] - w0);
        if (u < WIN) atomicAdd(&hbin[u], 1);
    }
    __syncthreads();
    for (int i = threadIdx.x; i < WIN; i += 1024)
        hist[c * N_NODES + w0 + i] = hbin[i];
}

// ---------------------------------------------------------------------------
// k_scan1: per-dst degree (sum over chunks) + per-block exclusive scan
// ---------------------------------------------------------------------------
__global__ __launch_bounds__(256) void k_scan1(
        const int* __restrict__ hist, int* __restrict__ pre,
        int* __restrict__ bsum) {
    __shared__ int sh[256];
    const int t = threadIdx.x;
    const int i = blockIdx.x * 256 + t;
    int v = 0;
    if (i < N_NODES)
        for (int c = 0; c < NCHUNK; ++c) v += hist[c * N_NODES + i];
    sh[t] = v;
    __syncthreads();
    for (int d = 1; d < 256; d <<= 1) {
        int u = (t >= d) ? sh[t - d] : 0;
        __syncthreads();
        sh[t] += u;
        __syncthreads();
    }
    if (i < N_NODES) pre[i] = sh[t] - v;
    if (t == 255) bsum[blockIdx.x] = sh[255];
}

// ---------------------------------------------------------------------------
// k_base: fuses the bsum scan (each block reduces bsum[0..b)) and turns
// hist[c][d] into scatter bases; emits final off[] (off[N]=N_EDGES).
// ---------------------------------------------------------------------------
__global__ __launch_bounds__(256) void k_base(
        const int* __restrict__ pre, const int* __restrict__ bsum,
        int* __restrict__ hist, int* __restrict__ off) {
    __shared__ int part[4];
    __shared__ int sbb;
    const int t = threadIdx.x, b = blockIdx.x;
    int v = (t < b) ? bsum[t] : 0;             // b <= 195 < 256
#pragma unroll
    for (int o = 32; o; o >>= 1) v += __shfl_xor(v, o);
    if ((t & 63) == 0) part[t >> 6] = v;
    __syncthreads();
    if (t == 0) sbb = part[0] + part[1] + part[2] + part[3];
    __syncthreads();
    const int bb = sbb;
    int d = b * 256 + t;
    if (d < N_NODES) {
        int run = pre[d] + bb;
        off[d] = run;
        for (int c = 0; c < NCHUNK; ++c) {
            int t0 = hist[c * N_NODES + d];
            hist[c * N_NODES + d] = run;
            run += t0;
        }
    }
    if (b == 0 && t == 0) off[N_NODES] = N_EDGES;
}

// ---------------------------------------------------------------------------
// k_scatter: (chunk, window) blocks; positions via LDS atomics on bases.
// Window csr region ~1.6 MB stays L2-resident.
// ---------------------------------------------------------------------------
__global__ __launch_bounds__(1024) void k_scatter(
        const int* __restrict__ s32, const int* __restrict__ d32,
        const int* __restrict__ hist, int* __restrict__ csr) {
    __shared__ int pos[WIN];                   // 50 KB
    const int c = blockIdx.x, w = blockIdx.y;
    const int w0 = w * WIN;
    for (int i = threadIdx.x; i < WIN; i += 1024)
        pos[i] = hist[c * N_NODES + w0 + i];
    __syncthreads();
    for (int e = c * CE + threadIdx.x; e < (c + 1) * CE; e += 1024) {
        unsigned u = (unsigned)(d32[e] - w0);
        if (u < WIN) {
            int p = atomicAdd(&pos[u], 1);
            csr[p] = s32[e];
        }
    }
}

// ---------------------------------------------------------------------------
// k_node, head-split: grid (3125, 4 heads), y slowest -> head-major dispatch.
// Per head the hot set (Whh head table 3.2 MB + sv head table 400 KB) fits
// the 4 MB per-XCD L2. 16 lanes per (node,head): softmax over deg edges,
// then 32-col accumulation (one 64 B Whh row per edge, coalesced).
// ---------------------------------------------------------------------------
__global__ __launch_bounds__(256) void k_node(
        const int* __restrict__ off, const int* __restrict__ csr,
        const float* __restrict__ sv, const __hip_bfloat16* __restrict__ Whh,
        float* __restrict__ invh, float* __restrict__ out_h) {
    __shared__ int   sbuf[16][CAP];            // 6 KB
    __shared__ float exb[16][CAP];             // 6 KB
    const int t    = threadIdx.x;
    const int slot = t >> 4;                   // 16 (node) slots per block
    const int q    = t & 15;                   // lane within quarter-wave
    const int h    = blockIdx.y;
    const int n    = blockIdx.x * 16 + slot;
    const int beg = off[n], end = off[n + 1], deg = end - beg;

    const float sdh = sv[((size_t)h * N_NODES + n) * 2 + 1];

    // Phase A: ex = exp(lrelu(s_src[src] + s_dst[n])); cache; sum (16-lane)
    float sum = 0.f;
    for (int l = q; l < deg; l += 16) {
        int s = csr[beg + l];
        float ss = sv[((size_t)h * N_NODES + s) * 2];
        float ex = __expf(lrelu(ss + sdh));
        if (l < CAP) { sbuf[slot][l] = s; exb[slot][l] = ex; }
        sum += ex;
    }
#pragma unroll
    for (int o = 8; o; o >>= 1) sum += __shfl_xor(sum, o);
    const float inv = 1.0f / (sum + 1e-9f);
    if (q == 0) invh[(size_t)h * N_NODES + n] = inv;

    // Phase D: out[n, h*32 + 2q..2q+1] = sum_j alpha_j * Whh[h][src_j][..]
    const __hip_bfloat16* wbase = Whh + (size_t)h * N_NODES * 32 + 2 * q;
    float2 acc = {0.f, 0.f};
    const int dc = deg < CAP ? deg : CAP;
    int j = 0;
    for (; j + 3 < dc; j += 4) {
        int s0 = sbuf[slot][j],     s1 = sbuf[slot][j + 1];
        int s2 = sbuf[slot][j + 2], s3 = sbuf[slot][j + 3];
        float a0 = exb[slot][j] * inv,     a1 = exb[slot][j + 1] * inv;
        float a2 = exb[slot][j + 2] * inv, a3 = exb[slot][j + 3] * inv;
        __hip_bfloat162 w0 = *(const __hip_bfloat162*)(wbase + (size_t)s0 * 32);
        __hip_bfloat162 w1 = *(const __hip_bfloat162*)(wbase + (size_t)s1 * 32);
        __hip_bfloat162 w2 = *(const __hip_bfloat162*)(wbase + (size_t)s2 * 32);
        __hip_bfloat162 w3 = *(const __hip_bfloat162*)(wbase + (size_t)s3 * 32);
        float2 f0 = __bfloat1622float2(w0);
        float2 f1 = __bfloat1622float2(w1);
        float2 f2 = __bfloat1622float2(w2);
        float2 f3 = __bfloat1622float2(w3);
        acc.x += a0 * f0.x + a1 * f1.x + a2 * f2.x + a3 * f3.x;
        acc.y += a0 * f0.y + a1 * f1.y + a2 * f2.y + a3 * f3.y;
    }
    for (; j < dc; ++j) {
        int s0 = sbuf[slot][j];
        float a0 = exb[slot][j] * inv;
        __hip_bfloat162 w0 = *(const __hip_bfloat162*)(wbase + (size_t)s0 * 32);
        float2 f0 = __bfloat1622float2(w0);
        acc.x += a0 * f0.x;
        acc.y += a0 * f0.y;
    }
    for (; j < deg; ++j) {                     // deg > CAP fallback (never hot)
        int s0 = csr[beg + j];
        float ss = sv[((size_t)h * N_NODES + s0) * 2];
        float a0 = __expf(lrelu(ss + sdh)) * inv;
        __hip_bfloat162 w0 = *(const __hip_bfloat162*)(wbase + (size_t)s0 * 32);
        float2 f0 = __bfloat1622float2(w0);
        acc.x += a0 * f0.x;
        acc.y += a0 * f0.y;
    }
    *(float2*)(out_h + (size_t)n * WH_DIM + h * 32 + 2 * q) = acc;
}

// ---------------------------------------------------------------------------
// Edge-parallel alpha: coalesced edge reads; gathers hit 2.4 MB of
// L2-resident sv/invh tables; coalesced float4 write.
// ---------------------------------------------------------------------------
__global__ __launch_bounds__(256) void k_alpha(
        const int* __restrict__ s32, const int* __restrict__ d32,
        const float* __restrict__ sv, const float* __restrict__ invh,
        float* __restrict__ ebuf) {
    int e = blockIdx.x * 256 + threadIdx.x;
    if (e >= N_EDGES) return;
    int s = s32[e], d = d32[e];
    float4 a;
#pragma unroll
    for (int h = 0; h < 4; ++h) {
        float ss = sv[((size_t)h * N_NODES + s) * 2];
        float sd = sv[((size_t)h * N_NODES + d) * 2 + 1];
        float iv = invh[(size_t)h * N_NODES + d];
        ((float*)&a)[h] = __expf(lrelu(ss + sd)) * iv;
    }
    *(float4*)(ebuf + (size_t)e * 4) = a;
}

// ---------------------------------------------------------------------------
extern "C" void kernel_launch(void* const* d_in, const int* in_sizes, int n_in,
                              void* d_out, int out_size, void* d_ws, size_t ws_size,
                              hipStream_t stream) {
    const float* x      = (const float*)d_in[0];
    const void*  eidx   = d_in[1];
    const float* weight = (const float*)d_in[2];
    const float* attn   = (const float*)d_in[3];

    float* out   = (float*)d_out;
    float* out_h = out;                                   // [N_NODES, 128]
    float* ebuf  = out + (size_t)N_NODES * WH_DIM;        // [N_EDGES, 4] alpha

    // workspace layout (64-B aligned); total ~41.2 MB
    char* ws = (char*)d_ws;
    int*   flag  = (int*)ws;                              // 64 B
    int*   bsum  = (int*)(ws + 64);                       // 784 B
    int*   off   = (int*)(ws + 1024);                     // 200004 B
    int*   pre   = (int*)(ws + 201088);                   // 200000 B
    int*   s32   = (int*)(ws + 401088);                   // 6.4 MB
    int*   d32   = (int*)(ws + 6801088);                  // 6.4 MB
    int*   hist  = (int*)(ws + 13201088);                 // 6.4 MB [c][d]
    int*   csr   = (int*)(ws + 19601088);                 // 6.4 MB
    __hip_bfloat16* Whh = (__hip_bfloat16*)(ws + 26001088);   // 12.8 MB [h][n][32]
    float* sv    = (float*)(ws + 38801088);               // 1.6 MB [h][n]{src,dst}
    float* invh  = (float*)(ws + 40401088);               // 0.8 MB [h][n]

    k_detect<<<1, 256, 0, stream>>>((const int*)eidx, flag);
    k_cvt<<<(N_EDGES + 255) / 256, 256, 0, stream>>>(eidx, flag, s32, d32);
    k_wh<<<(N_NODES + 63) / 64, 256, 0, stream>>>(x, weight, attn, Whh, sv);
    dim3 hg(NCHUNK, NPASS);
    k_hist<<<hg, 1024, 0, stream>>>(d32, hist);
    k_scan1<<<NB_SCAN, 256, 0, stream>>>(hist, pre, bsum);
    k_base<<<NB_SCAN, 256, 0, stream>>>(pre, bsum, hist, off);
    k_scatter<<<hg, 1024, 0, stream>>>(s32, d32, hist, csr);
    dim3 ng(N_NODES / 16, N_HEADS);
    k_node<<<ng, 256, 0, stream>>>(off, csr, sv, Whh, invh, out_h);
    k_alpha<<<(N_EDGES + 255) / 256, 256, 0, stream>>>(s32, d32, sv, invh, ebuf);
}

// Round 8
// 304.080 us; speedup vs baseline: 1.1019x; 1.1019x over previous
//
#include <hip/hip_runtime.h>
#include <hip/hip_bf16.h>
#include <math.h>

#define N_NODES 50000
#define N_EDGES 1600000
#define IN_DIM  128
#define OUT_DIM 32
#define N_HEADS 4
#define WH_DIM  (N_HEADS * OUT_DIM)   // 128
#define CAP     96                    // per-node LDS edge cache (max deg ~58)
#define NB_SCAN 196                   // ceil(50000/256)
#define NPASS   4                     // dst-windows
#define WIN     (N_NODES / NPASS)     // 12500
#define NCHUNK  32                    // edge chunks for counting sort
#define CE      (N_EDGES / NCHUNK)    // 50000 edges per chunk

typedef __attribute__((ext_vector_type(8))) short short8;     // 8 bf16
typedef __attribute__((ext_vector_type(4))) float floatx4;    // MFMA acc

__device__ __forceinline__ short f2bf(float v) {
    __hip_bfloat16 b = __float2bfloat16(v);
    return *reinterpret_cast<short*>(&b);
}
__device__ __forceinline__ float lrelu(float v) {
    return v > 0.0f ? v : 0.2f * v;
}

// ---------------------------------------------------------------------------
// edge_index may arrive as int32 or int64 (reference dtype). For int64, odd
// 32-bit words are zero hi-words; sample 256 of them.
// ---------------------------------------------------------------------------
__device__ __forceinline__ void load_edge(const void* eidx, int is32, int e,
                                          int& s, int& d) {
    if (is32) {
        const int2 v = ((const int2*)eidx)[e];
        s = v.x; d = v.y;
    } else {
        const longlong2 v = ((const longlong2*)eidx)[e];
        s = (int)v.x; d = (int)v.y;
    }
}

__global__ void k_detect(const int* __restrict__ eidx, int* __restrict__ flag) {
    __shared__ int sf;
    if (threadIdx.x == 0) sf = 0;
    __syncthreads();
    int r = eidx[2 * (threadIdx.x * (N_EDGES / 256)) + 1];
    if (r != 0) sf = 1;                        // benign race, all write 1
    __syncthreads();
    if (threadIdx.x == 0) *flag = sf;          // nonzero hi-word => int32
}

// ---------------------------------------------------------------------------
// k_cvt: canonicalize edges to int32 SoA (coalesced, no atomics)
// ---------------------------------------------------------------------------
__global__ __launch_bounds__(256) void k_cvt(
        const void* __restrict__ eidx, const int* __restrict__ flag,
        int* __restrict__ s32, int* __restrict__ d32) {
    int e = blockIdx.x * 256 + threadIdx.x;
    if (e >= N_EDGES) return;
    int s, d;
    load_edge(eidx, *flag, e, s, d);
    s32[e] = s;
    d32[e] = d;
}

// ---------------------------------------------------------------------------
// MFMA GEMM: [64 nodes] x [144 cols] per block, K=128, bf16 inputs.
//   cols   0..127 : Wh, stored HEAD-MAJOR: Whh[h][n][32] bf16
//   cols 128..135 : s = x . U ;  U[k][c] = sum_o W[h][k][o]*a[h][o]
//                   (c<4: a_src head c ; c>=4: a_dst head c-4)
//   s stored twice: sv[side][h][n] (4 B granules, for k_node) and the dst
//   side also into sdi[n][0..3] (32 B AoS rows, for k_alpha).
// ---------------------------------------------------------------------------
__global__ __launch_bounds__(256) void k_wh(
        const float* __restrict__ x, const float* __restrict__ weight,
        const float* __restrict__ attn,
        __hip_bfloat16* __restrict__ Whh, float* __restrict__ sv,
        float* __restrict__ sdi) {
    __shared__ float ubuf[128 * 8];            // 4 KB
    __shared__ short xsw[4 * 4 * 64 * 8];      // 16 KB  [wg][kc][lane][j]
    __shared__ short bsw[4 * 9 * 64 * 8];      // 36 KB  [kc][cg][lane][j]
    const int t  = threadIdx.x;
    const int nb = blockIdx.x * 64;

    // ---- U[k][c], c in [0,8)
    {
        int c = t & 7, k0 = t >> 3;            // k0 in [0,32)
        int h = c & 3;
        const float* ap = attn + h * 64 + (c >> 2) * 32;
        for (int k = k0; k < 128; k += 32) {
            const float* wp = weight + h * (IN_DIM * OUT_DIM) + k * OUT_DIM;
            float u = 0.f;
#pragma unroll
            for (int o = 0; o < 32; o += 4) {
                float4 wv = *(const float4*)(wp + o);
                float4 av = *(const float4*)(ap + o);
                u += wv.x * av.x + wv.y * av.y + wv.z * av.z + wv.w * av.w;
            }
            ubuf[k * 8 + c] = u;
        }
    }
    __syncthreads();

    // ---- stage B: weight cols 0..127
    for (int f = t; f < 128 * 128; f += 256) {
        int k = f >> 7, c = f & 127;
        float w = weight[(c >> 5) * (IN_DIM * OUT_DIM) + k * OUT_DIM + (c & 31)];
        int kc = k >> 5, quad = (k >> 3) & 3, j = k & 7;
        bsw[((kc * 9 + (c >> 4)) * 64 + quad * 16 + (c & 15)) * 8 + j] = f2bf(w);
    }
    // ---- stage B: extension cols 128..143 (U, zero-padded)
    for (int f = t; f < 128 * 16; f += 256) {
        int k = f >> 4, c = f & 15;
        float w = (c < 8) ? ubuf[k * 8 + c] : 0.f;
        int kc = k >> 5, quad = (k >> 3) & 3, j = k & 7;
        bsw[((kc * 9 + 8) * 64 + quad * 16 + c) * 8 + j] = f2bf(w);
    }
    // ---- stage A: 64 node rows of x, f32 -> bf16, swizzled
    for (int f = t; f < 64 * 32; f += 256) {
        int n = f >> 5, k = (f & 31) * 4;
        int ng = nb + n; if (ng > N_NODES - 1) ng = N_NODES - 1;
        float4 v = *(const float4*)(x + (size_t)ng * IN_DIM + k);
        int wg = n >> 4, m = n & 15, kc = k >> 5, quad = (k >> 3) & 3, j = k & 7;
        short4 sv4 = make_short4(f2bf(v.x), f2bf(v.y), f2bf(v.z), f2bf(v.w));
        *(short4*)&xsw[(((wg * 4 + kc) * 64) + quad * 16 + m) * 8 + j] = sv4;
    }
    __syncthreads();

    // ---- compute: per wave, 16 nodes x 144 cols, 36 MFMAs
    const int wg = t >> 6, lane = t & 63;
    floatx4 acc[9];
#pragma unroll
    for (int i = 0; i < 9; ++i) acc[i] = (floatx4){0.f, 0.f, 0.f, 0.f};
#pragma unroll
    for (int kc = 0; kc < 4; ++kc) {
        short8 a = *(short8*)&xsw[((wg * 4 + kc) * 64 + lane) * 8];
#pragma unroll
        for (int cg = 0; cg < 9; ++cg) {
            short8 b = *(short8*)&bsw[((kc * 9 + cg) * 64 + lane) * 8];
            acc[cg] = __builtin_amdgcn_mfma_f32_16x16x32_bf16(a, b, acc[cg],
                                                              0, 0, 0);
        }
    }

    // ---- epilogue (head-major stores)
    const int col = lane & 15, quad = lane >> 4;
#pragma unroll
    for (int r = 0; r < 4; ++r) {
        int n = nb + wg * 16 + quad * 4 + r;
        if (n >= N_NODES) continue;
#pragma unroll
        for (int cg = 0; cg < 8; ++cg)
            Whh[((size_t)(cg >> 1) * N_NODES + n) * 32 + (cg & 1) * 16 + col] =
                __float2bfloat16(acc[cg][r]);
        if (col < 8) {
            int hh = col & 3, side = col >> 2;
            sv[(size_t)side * 4 * N_NODES + (size_t)hh * N_NODES + n] =
                acc[8][r];
            if (side == 1) sdi[n * 8 + hh] = acc[8][r];
        }
    }
}

// ---------------------------------------------------------------------------
// k_hist: (chunk, window) blocks; LDS histogram, coalesced flush, no atomics.
// ---------------------------------------------------------------------------
__global__ __launch_bounds__(1024) void k_hist(
        const int* __restrict__ d32, int* __restrict__ hist) {
    __shared__ int hbin[WIN];                  // 50 KB
    const int c = blockIdx.x, w = blockIdx.y;
    for (int i = threadIdx.x; i < WIN; i += 1024) hbin[i] = 0;
    __syncthreads();
    const int w0 = w * WIN;
    for (int e = c * CE + threadIdx.x; e < (c + 1) * CE; e += 1024) {
        unsigned u = (unsigned)(d32[e] - w0);
        if (u < WIN) atomicAdd(&hbin[u], 1);
    }
    __syncthreads();
    for (int i = threadIdx.x; i < WIN; i += 1024)
        hist[c * N_NODES + w0 + i] = hbin[i];
}

// ---------------------------------------------------------------------------
// k_scan1: per-dst degree (sum over chunks) + per-block exclusive scan
// ---------------------------------------------------------------------------
__global__ __launch_bounds__(256) void k_scan1(
        const int* __restrict__ hist, int* __restrict__ pre,
        int* __restrict__ bsum) {
    __shared__ int sh[256];
    const int t = threadIdx.x;
    const int i = blockIdx.x * 256 + t;
    int v = 0;
    if (i < N_NODES)
        for (int c = 0; c < NCHUNK; ++c) v += hist[c * N_NODES + i];
    sh[t] = v;
    __syncthreads();
    for (int d = 1; d < 256; d <<= 1) {
        int u = (t >= d) ? sh[t - d] : 0;
        __syncthreads();
        sh[t] += u;
        __syncthreads();
    }
    if (i < N_NODES) pre[i] = sh[t] - v;
    if (t == 255) bsum[blockIdx.x] = sh[255];
}

// ---------------------------------------------------------------------------
// k_base: fuses the bsum scan (each block reduces bsum[0..b)) and turns
// hist[c][d] into scatter bases; emits final off[] (off[N]=N_EDGES).
// ---------------------------------------------------------------------------
__global__ __launch_bounds__(256) void k_base(
        const int* __restrict__ pre, const int* __restrict__ bsum,
        int* __restrict__ hist, int* __restrict__ off) {
    __shared__ int part[4];
    __shared__ int sbb;
    const int t = threadIdx.x, b = blockIdx.x;
    int v = (t < b) ? bsum[t] : 0;             // b <= 195 < 256
#pragma unroll
    for (int o = 32; o; o >>= 1) v += __shfl_xor(v, o);
    if ((t & 63) == 0) part[t >> 6] = v;
    __syncthreads();
    if (t == 0) sbb = part[0] + part[1] + part[2] + part[3];
    __syncthreads();
    const int bb = sbb;
    int d = b * 256 + t;
    if (d < N_NODES) {
        int run = pre[d] + bb;
        off[d] = run;
        for (int c = 0; c < NCHUNK; ++c) {
            int t0 = hist[c * N_NODES + d];
            hist[c * N_NODES + d] = run;
            run += t0;
        }
    }
    if (b == 0 && t == 0) off[N_NODES] = N_EDGES;
}

// ---------------------------------------------------------------------------
// k_scatter: (chunk, window) blocks; positions via LDS atomics on bases.
// Window csr region ~1.6 MB stays L2-resident.
// ---------------------------------------------------------------------------
__global__ __launch_bounds__(1024) void k_scatter(
        const int* __restrict__ s32, const int* __restrict__ d32,
        const int* __restrict__ hist, int* __restrict__ csr) {
    __shared__ int pos[WIN];                   // 50 KB
    const int c = blockIdx.x, w = blockIdx.y;
    const int w0 = w * WIN;
    for (int i = threadIdx.x; i < WIN; i += 1024)
        pos[i] = hist[c * N_NODES + w0 + i];
    __syncthreads();
    for (int e = c * CE + threadIdx.x; e < (c + 1) * CE; e += 1024) {
        unsigned u = (unsigned)(d32[e] - w0);
        if (u < WIN) {
            int p = atomicAdd(&pos[u], 1);
            csr[p] = s32[e];
        }
    }
}

// ---------------------------------------------------------------------------
// k_node, head-split: grid (3125, 4 heads), y slowest -> head-major dispatch.
// Per head the hot set (Whh head 3.2 MB + sv_src head 200 KB) fits the 4 MB
// per-XCD L2. 16 lanes per (node,head). Writes inv into sdi[n][4+h].
// ---------------------------------------------------------------------------
__global__ __launch_bounds__(256) void k_node(
        const int* __restrict__ off, const int* __restrict__ csr,
        const float* __restrict__ sv, const __hip_bfloat16* __restrict__ Whh,
        float* __restrict__ sdi, float* __restrict__ out_h) {
    __shared__ int   sbuf[16][CAP];            // 6 KB
    __shared__ float exb[16][CAP];             // 6 KB
    const int t    = threadIdx.x;
    const int slot = t >> 4;                   // 16 (node) slots per block
    const int q    = t & 15;                   // lane within quarter-wave
    const int h    = blockIdx.y;
    const int n    = blockIdx.x * 16 + slot;
    const int beg = off[n], end = off[n + 1], deg = end - beg;

    const float* svs = sv + (size_t)h * N_NODES;                  // src side
    const float sdh  = sv[(size_t)4 * N_NODES + (size_t)h * N_NODES + n];

    // Phase A: ex = exp(lrelu(s_src[src] + s_dst[n])); cache; sum (16-lane)
    float sum = 0.f;
    for (int l = q; l < deg; l += 16) {
        int s = csr[beg + l];
        float ex = __expf(lrelu(svs[s] + sdh));
        if (l < CAP) { sbuf[slot][l] = s; exb[slot][l] = ex; }
        sum += ex;
    }
#pragma unroll
    for (int o = 8; o; o >>= 1) sum += __shfl_xor(sum, o);
    const float inv = 1.0f / (sum + 1e-9f);
    if (q == 0) sdi[n * 8 + 4 + h] = inv;

    // Phase D: out[n, h*32 + 2q..2q+1] = sum_j alpha_j * Whh[h][src_j][..]
    const __hip_bfloat16* wbase = Whh + (size_t)h * N_NODES * 32 + 2 * q;
    float2 acc = {0.f, 0.f};
    const int dc = deg < CAP ? deg : CAP;
    int j = 0;
    for (; j + 3 < dc; j += 4) {
        int s0 = sbuf[slot][j],     s1 = sbuf[slot][j + 1];
        int s2 = sbuf[slot][j + 2], s3 = sbuf[slot][j + 3];
        float a0 = exb[slot][j] * inv,     a1 = exb[slot][j + 1] * inv;
        float a2 = exb[slot][j + 2] * inv, a3 = exb[slot][j + 3] * inv;
        __hip_bfloat162 w0 = *(const __hip_bfloat162*)(wbase + (size_t)s0 * 32);
        __hip_bfloat162 w1 = *(const __hip_bfloat162*)(wbase + (size_t)s1 * 32);
        __hip_bfloat162 w2 = *(const __hip_bfloat162*)(wbase + (size_t)s2 * 32);
        __hip_bfloat162 w3 = *(const __hip_bfloat162*)(wbase + (size_t)s3 * 32);
        float2 f0 = __bfloat1622float2(w0);
        float2 f1 = __bfloat1622float2(w1);
        float2 f2 = __bfloat1622float2(w2);
        float2 f3 = __bfloat1622float2(w3);
        acc.x += a0 * f0.x + a1 * f1.x + a2 * f2.x + a3 * f3.x;
        acc.y += a0 * f0.y + a1 * f1.y + a2 * f2.y + a3 * f3.y;
    }
    for (; j < dc; ++j) {
        int s0 = sbuf[slot][j];
        float a0 = exb[slot][j] * inv;
        __hip_bfloat162 w0 = *(const __hip_bfloat162*)(wbase + (size_t)s0 * 32);
        float2 f0 = __bfloat1622float2(w0);
        acc.x += a0 * f0.x;
        acc.y += a0 * f0.y;
    }
    for (; j < deg; ++j) {                     // deg > CAP fallback (never hot)
        int s0 = csr[beg + j];
        float a0 = __expf(lrelu(svs[s0] + sdh)) * inv;
        __hip_bfloat162 w0 = *(const __hip_bfloat162*)(wbase + (size_t)s0 * 32);
        float2 f0 = __bfloat1622float2(w0);
        acc.x += a0 * f0.x;
        acc.y += a0 * f0.y;
    }
    *(float2*)(out_h + (size_t)n * WH_DIM + h * 32 + 2 * q) = acc;
}

// ---------------------------------------------------------------------------
// Edge-parallel alpha: coalesced edge reads; s-side = 4 scalar gathers in the
// 800 KB sv_src table; d-side = one 32 B granule (sd4+inv4) from sdi[d];
// coalesced float4 write.
// ---------------------------------------------------------------------------
__global__ __launch_bounds__(256) void k_alpha(
        const int* __restrict__ s32, const int* __restrict__ d32,
        const float* __restrict__ sv, const float* __restrict__ sdi,
        float* __restrict__ ebuf) {
    int e = blockIdx.x * 256 + threadIdx.x;
    if (e >= N_EDGES) return;
    int s = s32[e], d = d32[e];
    float4 sd4 = *(const float4*)(sdi + (size_t)d * 8);
    float4 iv4 = *(const float4*)(sdi + (size_t)d * 8 + 4);
    float4 a;
    a.x = __expf(lrelu(sv[s]                   + sd4.x)) * iv4.x;
    a.y = __expf(lrelu(sv[N_NODES + s]         + sd4.y)) * iv4.y;
    a.z = __expf(lrelu(sv[2 * N_NODES + s]     + sd4.z)) * iv4.z;
    a.w = __expf(lrelu(sv[3 * N_NODES + s]     + sd4.w)) * iv4.w;
    *(float4*)(ebuf + (size_t)e * 4) = a;
}

// ---------------------------------------------------------------------------
extern "C" void kernel_launch(void* const* d_in, const int* in_sizes, int n_in,
                              void* d_out, int out_size, void* d_ws, size_t ws_size,
                              hipStream_t stream) {
    const float* x      = (const float*)d_in[0];
    const void*  eidx   = d_in[1];
    const float* weight = (const float*)d_in[2];
    const float* attn   = (const float*)d_in[3];

    float* out   = (float*)d_out;
    float* out_h = out;                                   // [N_NODES, 128]
    float* ebuf  = out + (size_t)N_NODES * WH_DIM;        // [N_EDGES, 4] alpha

    // workspace layout (64-B aligned); total ~42.0 MB
    char* ws = (char*)d_ws;
    int*   flag  = (int*)ws;                              // 64 B
    int*   bsum  = (int*)(ws + 64);                       // 784 B
    int*   off   = (int*)(ws + 1024);                     // 200004 B
    int*   pre   = (int*)(ws + 201088);                   // 200000 B
    int*   s32   = (int*)(ws + 401088);                   // 6.4 MB
    int*   d32   = (int*)(ws + 6801088);                  // 6.4 MB
    int*   hist  = (int*)(ws + 13201088);                 // 6.4 MB [c][d]
    int*   csr   = (int*)(ws + 19601088);                 // 6.4 MB
    __hip_bfloat16* Whh = (__hip_bfloat16*)(ws + 26001088);   // 12.8 MB [h][n][32]
    float* sv    = (float*)(ws + 38801088);               // 1.6 MB [side][h][n]
    float* sdi   = (float*)(ws + 40401088);               // 1.6 MB [n]{sd4,inv4}

    k_detect<<<1, 256, 0, stream>>>((const int*)eidx, flag);
    k_cvt<<<(N_EDGES + 255) / 256, 256, 0, stream>>>(eidx, flag, s32, d32);
    k_wh<<<(N_NODES + 63) / 64, 256, 0, stream>>>(x, weight, attn, Whh, sv, sdi);
    dim3 hg(NCHUNK, NPASS);
    k_hist<<<hg, 1024, 0, stream>>>(d32, hist);
    k_scan1<<<NB_SCAN, 256, 0, stream>>>(hist, pre, bsum);
    k_base<<<NB_SCAN, 256, 0, stream>>>(pre, bsum, hist, off);
    k_scatter<<<hg, 1024, 0, stream>>>(s32, d32, hist, csr);
    dim3 ng(N_NODES / 16, N_HEADS);
    k_node<<<ng, 256, 0, stream>>>(off, csr, sv, Whh, sdi, out_h);
    k_alpha<<<(N_EDGES + 255) / 256, 256, 0, stream>>>(s32, d32, sv, sdi, ebuf);
}